// Round 1
// baseline (877.539 us; speedup 1.0000x reference)
//
#include <hip/hip_runtime.h>
#include <hip/hip_bf16.h>

typedef __bf16 bf16_t;
typedef __bf16 bf16x8 __attribute__((ext_vector_type(8)));
typedef __bf16 bf16x4 __attribute__((ext_vector_type(4)));
typedef float  f32x4  __attribute__((ext_vector_type(4)));
typedef __attribute__((address_space(3))) unsigned as3u32;
typedef __attribute__((address_space(1))) unsigned as1u32;

#define Bdim 4
#define Sdim 2048
#define Ddim 1024
#define Edim 2048

__device__ __forceinline__ void gload_lds16(const void* g, void* l) {
  __builtin_amdgcn_global_load_lds((const as1u32*)g, (as3u32*)l, 16, 0, 0);
}

__device__ __forceinline__ float sigmoidf_(float x) {
  return 1.f / (1.f + __expf(-x));
}

// ---------------- weight fp32 -> bf16 ----------------
__global__ __launch_bounds__(256)
void cvt_bf16(const float* __restrict__ s, bf16_t* __restrict__ d, int n) {
  int i = blockIdx.x * 256 + threadIdx.x;
  if (i < n) d[i] = (bf16_t)s[i];
}

// ---------------- scan scalars: a_e = exp(-softplus(ld)), C_e = dot(A[e],Bm[e]) ----
__global__ __launch_bounds__(256)
void prep_scalars(const float* __restrict__ ld, const float* __restrict__ Am,
                  const float* __restrict__ Bm, float* __restrict__ aexp,
                  float* __restrict__ Ce) {
  int e = blockIdx.x * 256 + threadIdx.x;
  if (e >= Edim) return;
  float d = ld[e];
  float sp = (d > 20.f) ? d : log1pf(expf(d));
  aexp[e] = expf(-sp);
  float s = 0.f;
  #pragma unroll
  for (int n = 0; n < 16; ++n) s += Am[e * 16 + n] * Bm[e * 16 + n];
  Ce[e] = s;
}

// ---------------- layernorm: one block per row of 1024 ----------------
__global__ __launch_bounds__(256)
void ln_kernel(const float* __restrict__ x, const float* __restrict__ g,
               const float* __restrict__ b, bf16_t* __restrict__ out) {
  const int row = blockIdx.x;
  const int tid = threadIdx.x;
  const float4 v = ((const float4*)(x + (size_t)row * Ddim))[tid];
  float s  = v.x + v.y + v.z + v.w;
  float ss = v.x * v.x + v.y * v.y + v.z * v.z + v.w * v.w;
  #pragma unroll
  for (int o = 32; o > 0; o >>= 1) { s += __shfl_down(s, o); ss += __shfl_down(ss, o); }
  __shared__ float sh[8];
  const int wv = tid >> 6, lane = tid & 63;
  if (lane == 0) { sh[wv] = s; sh[4 + wv] = ss; }
  __syncthreads();
  s  = sh[0] + sh[1] + sh[2] + sh[3];
  ss = sh[4] + sh[5] + sh[6] + sh[7];
  const float mean = s * (1.f / Ddim);
  const float var  = ss * (1.f / Ddim) - mean * mean;
  const float rstd = rsqrtf(var + 1e-5f);
  const float4 gv = ((const float4*)g)[tid];
  const float4 bv = ((const float4*)b)[tid];
  bf16x4 o;
  o[0] = (bf16_t)((v.x - mean) * rstd * gv.x + bv.x);
  o[1] = (bf16_t)((v.y - mean) * rstd * gv.y + bv.y);
  o[2] = (bf16_t)((v.z - mean) * rstd * gv.z + bv.z);
  o[3] = (bf16_t)((v.w - mean) * rstd * gv.w + bv.w);
  *(bf16x4*)(out + (size_t)row * Ddim + tid * 4) = o;
}

// ---------------- GEMM_BT: C[m,n] = sum_k A[m,k]*Bw[n,k] + bias[n] (+R, fp32 out) ---
#define BM 128
#define BN 128
#define BK 32

template<bool RES>
__global__ __launch_bounds__(256)
void gemm_bt(const bf16_t* __restrict__ A, const bf16_t* __restrict__ Bw,
             const float* __restrict__ bias, const float* __restrict__ R,
             bf16_t* __restrict__ Cb, float* __restrict__ Cf,
             int M, int N, int K) {
  __shared__ __align__(16) bf16_t As[BM * BK];
  __shared__ __align__(16) bf16_t Bs[BN * BK];

  const int tid  = threadIdx.x;
  const int lane = tid & 63;
  const int wv   = tid >> 6;
  const int m0   = blockIdx.y * BM;
  const int n0   = blockIdx.x * BN;

  const int wr = (wv >> 1) * 64;  // wave row offset
  const int wc = (wv & 1) * 64;   // wave col offset
  const int tq = lane >> 4;       // quad
  const int tr = lane & 15;

  f32x4 acc[4][4] = {};

  // staging: 512 x 16B chunks per 8KB tile; thread covers chunk tid and tid+256
  const int row0 = tid >> 2,        kp0 = (tid & 3) * 8;
  const int row1 = (tid + 256) >> 2, kp1 = (tid & 3) * 8;
  const size_t aBase = (size_t)m0 * K;
  const size_t bBase = (size_t)n0 * K;
  char* AsB = (char*)As;
  char* BsB = (char*)Bs;
  const int ldsOff0 = wv * 1024;         // wave-uniform base, chunk set 0
  const int ldsOff1 = 4096 + wv * 1024;  // chunk set 1

  for (int k0 = 0; k0 < K; k0 += BK) {
    __syncthreads();
    gload_lds16(A  + aBase + (size_t)row0 * K + k0 + kp0, AsB + ldsOff0);
    gload_lds16(A  + aBase + (size_t)row1 * K + k0 + kp1, AsB + ldsOff1);
    gload_lds16(Bw + bBase + (size_t)row0 * K + k0 + kp0, BsB + ldsOff0);
    gload_lds16(Bw + bBase + (size_t)row1 * K + k0 + kp1, BsB + ldsOff1);
    __syncthreads();

    bf16x8 af[4], bfr[4];
    #pragma unroll
    for (int i = 0; i < 4; ++i)
      af[i] = *(const bf16x8*)&As[(wr + i * 16 + tr) * BK + tq * 8];
    #pragma unroll
    for (int j = 0; j < 4; ++j)
      bfr[j] = *(const bf16x8*)&Bs[(wc + j * 16 + tr) * BK + tq * 8];
    #pragma unroll
    for (int i = 0; i < 4; ++i)
      #pragma unroll
      for (int j = 0; j < 4; ++j)
        acc[i][j] = __builtin_amdgcn_mfma_f32_16x16x32_bf16(af[i], bfr[j], acc[i][j], 0, 0, 0);
  }

  #pragma unroll
  for (int i = 0; i < 4; ++i) {
    #pragma unroll
    for (int j = 0; j < 4; ++j) {
      const int col = n0 + wc + j * 16 + tr;
      const float bv = bias[col];
      #pragma unroll
      for (int r = 0; r < 4; ++r) {
        const int rowg = m0 + wr + i * 16 + tq * 4 + r;
        const size_t idx = (size_t)rowg * N + col;
        const float v = acc[i][j][r] + bv;
        if (RES) Cf[idx] = v + R[idx];
        else     Cb[idx] = (bf16_t)v;
      }
    }
  }
}

// ---------------- causal depthwise conv (K=4) + silu ----------------
// xpg: (B*S, 2E) rows; xp = cols [0,E). xc out: (B*S, E)
__global__ __launch_bounds__(256)
void conv_silu(const bf16_t* __restrict__ xpg, const float* __restrict__ cw,
               const float* __restrict__ cb, bf16_t* __restrict__ xc) {
  const int e  = blockIdx.y * 256 + threadIdx.x;
  const int b  = blockIdx.x >> 9;          // 512 s-chunks of 4 per batch
  const int s0 = (blockIdx.x & 511) * 4;
  const float w0 = cw[e * 4 + 0], w1 = cw[e * 4 + 1], w2 = cw[e * 4 + 2], w3 = cw[e * 4 + 3];
  const float bias = cb[e];
  float xv[7];
  #pragma unroll
  for (int j = 0; j < 7; ++j) {
    const int s = s0 - 3 + j;
    xv[j] = (s >= 0) ? (float)xpg[(size_t)(b * Sdim + s) * (2 * Edim) + e] : 0.f;
  }
  #pragma unroll
  for (int t = 0; t < 4; ++t) {
    float a = fmaf(w0, xv[t], fmaf(w1, xv[t + 1], fmaf(w2, xv[t + 2], fmaf(w3, xv[t + 3], bias))));
    float y = a * sigmoidf_(a);
    xc[(size_t)(b * Sdim + s0 + t) * Edim + e] = (bf16_t)y;
  }
}

// ---------------- u = c * sigmoid(d), elementwise ----------------
__global__ __launch_bounds__(256)
void umul(const bf16_t* __restrict__ c, const bf16_t* __restrict__ d,
          bf16_t* __restrict__ u) {
  const size_t i = (size_t)blockIdx.x * 256 + threadIdx.x;
  u[i] = (bf16_t)((float)c[i] * sigmoidf_((float)d[i]));
}

// ---------------- scan + gate: z_t = a*z + u_t ; xg = C*z*sigmoid(gate) ----------
__global__ __launch_bounds__(256)
void scan_gate(const bf16_t* __restrict__ u, const bf16_t* __restrict__ xpg,
               const float* __restrict__ aexp, const float* __restrict__ Ce,
               bf16_t* __restrict__ xg) {
  const int idx = blockIdx.x * 256 + threadIdx.x;  // b*E + e
  const int b = idx >> 11, e = idx & (Edim - 1);
  const float a = aexp[e], C = Ce[e];
  const bf16_t* up = u   + (size_t)b * Sdim * Edim + e;
  const bf16_t* gp = xpg + (size_t)b * Sdim * (2 * Edim) + Edim + e;
  bf16_t*       op = xg  + (size_t)b * Sdim * Edim + e;
  float z = 0.f;
  for (int t = 0; t < Sdim; ++t) {
    z = fmaf(a, z, (float)up[(size_t)t * Edim]);
    const float gv = (float)gp[(size_t)t * (2 * Edim)];
    op[(size_t)t * Edim] = (bf16_t)(C * z * sigmoidf_(gv));
  }
}

extern "C" void kernel_launch(void* const* d_in, const int* in_sizes, int n_in,
                              void* d_out, int out_size, void* d_ws, size_t ws_size,
                              hipStream_t stream) {
  const float* x         = (const float*)d_in[0];
  const float* ln_g      = (const float*)d_in[1];
  const float* ln_b      = (const float*)d_in[2];
  const float* W_in      = (const float*)d_in[3];
  const float* b_in      = (const float*)d_in[4];
  const float* conv_w    = (const float*)d_in[5];
  const float* conv_b    = (const float*)d_in[6];
  const float* Am        = (const float*)d_in[7];
  const float* Bm        = (const float*)d_in[8];
  const float* W_c       = (const float*)d_in[9];
  const float* b_c       = (const float*)d_in[10];
  const float* W_d       = (const float*)d_in[11];
  const float* b_d       = (const float*)d_in[12];
  const float* log_delta = (const float*)d_in[13];
  const float* W_out     = (const float*)d_in[14];
  const float* b_out     = (const float*)d_in[15];
  float* out = (float*)d_out;

  const size_t MiB = 1024 * 1024;
  char* w = (char*)d_ws;
  bf16_t* wWin  = (bf16_t*)(w + 0);           //  8 MiB  (4096x1024)
  bf16_t* wWc   = (bf16_t*)(w + 8 * MiB);     //  8 MiB  (2048x2048)
  bf16_t* wWd   = (bf16_t*)(w + 16 * MiB);    //  8 MiB
  bf16_t* wWout = (bf16_t*)(w + 24 * MiB);    //  4 MiB  (1024x2048)
  float*  aexp  = (float*) (w + 28 * MiB);    //  8 KiB
  float*  Ce    = (float*) (w + 28 * MiB + 16384);
  bf16_t* xln   = (bf16_t*)(w + 29 * MiB);    // 16 MiB  (8192x1024)
  bf16_t* xpg   = (bf16_t*)(w + 45 * MiB);    // 64 MiB  (8192x4096)
  bf16_t* xc    = (bf16_t*)(w + 109 * MiB);   // 32 MiB  (8192x2048)
  bf16_t* cbuf  = (bf16_t*)(w + 141 * MiB);   // 32 MiB  (also u, in-place)
  bf16_t* dbuf  = (bf16_t*)(w + 173 * MiB);   // 32 MiB  (also xg) -> ends 205 MiB

  const int M = Bdim * Sdim;  // 8192

  // weights -> bf16
  cvt_bf16<<<(2 * Edim * Ddim) / 256, 256, 0, stream>>>(W_in, wWin, 2 * Edim * Ddim);
  cvt_bf16<<<(Edim * Edim) / 256, 256, 0, stream>>>(W_c, wWc, Edim * Edim);
  cvt_bf16<<<(Edim * Edim) / 256, 256, 0, stream>>>(W_d, wWd, Edim * Edim);
  cvt_bf16<<<(Ddim * Edim) / 256, 256, 0, stream>>>(W_out, wWout, Ddim * Edim);
  prep_scalars<<<Edim / 256, 256, 0, stream>>>(log_delta, Am, Bm, aexp, Ce);

  // layernorm
  ln_kernel<<<M, 256, 0, stream>>>(x, ln_g, ln_b, xln);

  // x_proj = x_ln @ W_in^T + b_in   -> xpg (bf16, 8192x4096)
  gemm_bt<false><<<dim3((2 * Edim) / BN, M / BM), 256, 0, stream>>>(
      xln, wWin, b_in, nullptr, xpg, nullptr, M, 2 * Edim, Ddim);

  // causal conv + silu -> xc
  conv_silu<<<dim3(Bdim * (Sdim / 4), Edim / 256), 256, 0, stream>>>(xpg, conv_w, conv_b, xc);

  // c = xc @ W_c^T + b_c ; d = xc @ W_d^T + b_d
  gemm_bt<false><<<dim3(Edim / BN, M / BM), 256, 0, stream>>>(
      xc, wWc, b_c, nullptr, cbuf, nullptr, M, Edim, Edim);
  gemm_bt<false><<<dim3(Edim / BN, M / BM), 256, 0, stream>>>(
      xc, wWd, b_d, nullptr, dbuf, nullptr, M, Edim, Edim);

  // u = c * sigmoid(d)  (in-place into cbuf)
  umul<<<(M * Edim) / 256, 256, 0, stream>>>(cbuf, dbuf, cbuf);

  // scan + gate -> xg (into dbuf)
  scan_gate<<<(Bdim * Edim) / 256, 256, 0, stream>>>(cbuf, xpg, aexp, Ce, dbuf);

  // out = xg @ W_out^T + b_out + x
  gemm_bt<true><<<dim3(Ddim / BN, M / BM), 256, 0, stream>>>(
      dbuf, wWout, b_out, x, nullptr, out, M, Ddim, Edim);

  (void)in_sizes; (void)n_in; (void)out_size; (void)ws_size;
}

// Round 2
// 612.433 us; speedup vs baseline: 1.4329x; 1.4329x over previous
//
#include <hip/hip_runtime.h>
#include <hip/hip_bf16.h>

typedef __bf16 bf16_t;
typedef __bf16 bf16x8 __attribute__((ext_vector_type(8)));
typedef __bf16 bf16x4 __attribute__((ext_vector_type(4)));
typedef float  f32x4  __attribute__((ext_vector_type(4)));
typedef __attribute__((address_space(3))) unsigned as3u32;
typedef __attribute__((address_space(1))) unsigned as1u32;

#define Bdim 4
#define Sdim 2048
#define Ddim 1024
#define Edim 2048
#define CH 64   // scan chunks
#define CL 32   // chunk length (CH*CL == Sdim)

__device__ __forceinline__ void gload_lds16(const void* g, void* l) {
  __builtin_amdgcn_global_load_lds((const as1u32*)g, (as3u32*)l, 16, 0, 0);
}

__device__ __forceinline__ float sigmoidf_(float x) {
  return 1.f / (1.f + __expf(-x));
}

// ---------------- weight fp32 -> bf16 ----------------
__global__ __launch_bounds__(256)
void cvt_bf16(const float* __restrict__ s, bf16_t* __restrict__ d, int n) {
  int i = blockIdx.x * 256 + threadIdx.x;
  if (i < n) d[i] = (bf16_t)s[i];
}

// ---------------- scan scalars: a_e = exp(-softplus(ld)), C_e = dot(A[e],Bm[e]) ----
__global__ __launch_bounds__(256)
void prep_scalars(const float* __restrict__ ld, const float* __restrict__ Am,
                  const float* __restrict__ Bm, float* __restrict__ aexp,
                  float* __restrict__ Ce) {
  int e = blockIdx.x * 256 + threadIdx.x;
  if (e >= Edim) return;
  float d = ld[e];
  float sp = (d > 20.f) ? d : log1pf(expf(d));
  aexp[e] = expf(-sp);
  float s = 0.f;
  #pragma unroll
  for (int n = 0; n < 16; ++n) s += Am[e * 16 + n] * Bm[e * 16 + n];
  Ce[e] = s;
}

// ---------------- layernorm: one block per row of 1024 ----------------
__global__ __launch_bounds__(256)
void ln_kernel(const float* __restrict__ x, const float* __restrict__ g,
               const float* __restrict__ b, bf16_t* __restrict__ out) {
  const int row = blockIdx.x;
  const int tid = threadIdx.x;
  const float4 v = ((const float4*)(x + (size_t)row * Ddim))[tid];
  float s  = v.x + v.y + v.z + v.w;
  float ss = v.x * v.x + v.y * v.y + v.z * v.z + v.w * v.w;
  #pragma unroll
  for (int o = 32; o > 0; o >>= 1) { s += __shfl_down(s, o); ss += __shfl_down(ss, o); }
  __shared__ float sh[8];
  const int wv = tid >> 6, lane = tid & 63;
  if (lane == 0) { sh[wv] = s; sh[4 + wv] = ss; }
  __syncthreads();
  s  = sh[0] + sh[1] + sh[2] + sh[3];
  ss = sh[4] + sh[5] + sh[6] + sh[7];
  const float mean = s * (1.f / Ddim);
  const float var  = ss * (1.f / Ddim) - mean * mean;
  const float rstd = rsqrtf(var + 1e-5f);
  const float4 gv = ((const float4*)g)[tid];
  const float4 bv = ((const float4*)b)[tid];
  bf16x4 o;
  o[0] = (bf16_t)((v.x - mean) * rstd * gv.x + bv.x);
  o[1] = (bf16_t)((v.y - mean) * rstd * gv.y + bv.y);
  o[2] = (bf16_t)((v.z - mean) * rstd * gv.z + bv.z);
  o[3] = (bf16_t)((v.w - mean) * rstd * gv.w + bv.w);
  *(bf16x4*)(out + (size_t)row * Ddim + tid * 4) = o;
}

// ---------------- GEMM_BT: acc = A @ Bw^T + bias ----------------
// MODE 0: Cb[idx] = bf16(acc+bias)
// MODE 1: Cf[idx] = acc+bias + R[idx]          (fp32 out, residual)
// MODE 2: Cb[idx] = bf16( X[idx] * sigmoid(acc+bias) )   (fused u = c*sigmoid(d))
#define BM 128
#define BN 128
#define BK 32

template<int MODE>
__global__ __launch_bounds__(256)
void gemm_bt(const bf16_t* __restrict__ A, const bf16_t* __restrict__ Bw,
             const float* __restrict__ bias, const float* __restrict__ R,
             const bf16_t* __restrict__ X,
             bf16_t* __restrict__ Cb, float* __restrict__ Cf,
             int M, int N, int K) {
  __shared__ __align__(16) bf16_t As[BM * BK];
  __shared__ __align__(16) bf16_t Bs[BN * BK];

  const int tid  = threadIdx.x;
  const int lane = tid & 63;
  const int wv   = tid >> 6;
  const int m0   = blockIdx.y * BM;
  const int n0   = blockIdx.x * BN;

  const int wr = (wv >> 1) * 64;  // wave row offset
  const int wc = (wv & 1) * 64;   // wave col offset
  const int tq = lane >> 4;       // quad
  const int tr = lane & 15;

  f32x4 acc[4][4] = {};

  const int row0 = tid >> 2,         kp0 = (tid & 3) * 8;
  const int row1 = (tid + 256) >> 2, kp1 = (tid & 3) * 8;
  const size_t aBase = (size_t)m0 * K;
  const size_t bBase = (size_t)n0 * K;
  char* AsB = (char*)As;
  char* BsB = (char*)Bs;
  const int ldsOff0 = wv * 1024;
  const int ldsOff1 = 4096 + wv * 1024;

  for (int k0 = 0; k0 < K; k0 += BK) {
    __syncthreads();
    gload_lds16(A  + aBase + (size_t)row0 * K + k0 + kp0, AsB + ldsOff0);
    gload_lds16(A  + aBase + (size_t)row1 * K + k0 + kp1, AsB + ldsOff1);
    gload_lds16(Bw + bBase + (size_t)row0 * K + k0 + kp0, BsB + ldsOff0);
    gload_lds16(Bw + bBase + (size_t)row1 * K + k0 + kp1, BsB + ldsOff1);
    __syncthreads();

    bf16x8 af[4], bfr[4];
    #pragma unroll
    for (int i = 0; i < 4; ++i)
      af[i] = *(const bf16x8*)&As[(wr + i * 16 + tr) * BK + tq * 8];
    #pragma unroll
    for (int j = 0; j < 4; ++j)
      bfr[j] = *(const bf16x8*)&Bs[(wc + j * 16 + tr) * BK + tq * 8];
    #pragma unroll
    for (int i = 0; i < 4; ++i)
      #pragma unroll
      for (int j = 0; j < 4; ++j)
        acc[i][j] = __builtin_amdgcn_mfma_f32_16x16x32_bf16(af[i], bfr[j], acc[i][j], 0, 0, 0);
  }

  #pragma unroll
  for (int i = 0; i < 4; ++i) {
    #pragma unroll
    for (int j = 0; j < 4; ++j) {
      const int col = n0 + wc + j * 16 + tr;
      const float bv = bias[col];
      #pragma unroll
      for (int r = 0; r < 4; ++r) {
        const int rowg = m0 + wr + i * 16 + tq * 4 + r;
        const size_t idx = (size_t)rowg * N + col;
        const float v = acc[i][j][r] + bv;
        if (MODE == 1)      Cf[idx] = v + R[idx];
        else if (MODE == 2) Cb[idx] = (bf16_t)((float)X[idx] * sigmoidf_(v));
        else                Cb[idx] = (bf16_t)v;
      }
    }
  }
}

// ---------------- causal depthwise conv (K=4) + silu ----------------
__global__ __launch_bounds__(256)
void conv_silu(const bf16_t* __restrict__ xpg, const float* __restrict__ cw,
               const float* __restrict__ cb, bf16_t* __restrict__ xc) {
  const int e  = blockIdx.y * 256 + threadIdx.x;
  const int b  = blockIdx.x >> 9;
  const int s0 = (blockIdx.x & 511) * 4;
  const float w0 = cw[e * 4 + 0], w1 = cw[e * 4 + 1], w2 = cw[e * 4 + 2], w3 = cw[e * 4 + 3];
  const float bias = cb[e];
  float xv[7];
  #pragma unroll
  for (int j = 0; j < 7; ++j) {
    const int s = s0 - 3 + j;
    xv[j] = (s >= 0) ? (float)xpg[(size_t)(b * Sdim + s) * (2 * Edim) + e] : 0.f;
  }
  #pragma unroll
  for (int t = 0; t < 4; ++t) {
    float a = fmaf(w0, xv[t], fmaf(w1, xv[t + 1], fmaf(w2, xv[t + 2], fmaf(w3, xv[t + 3], bias))));
    float y = a * sigmoidf_(a);
    xc[(size_t)(b * Sdim + s0 + t) * Edim + e] = (bf16_t)y;
  }
}

// ---------------- chunked parallel scan ----------------
// Phase 1: per-(b,e,chunk) local scan end value (from zero state)
__global__ __launch_bounds__(256)
void scan_part1(const bf16_t* __restrict__ u, const float* __restrict__ aexp,
                float* __restrict__ zloc) {
  const int c    = blockIdx.x;
  const int b    = blockIdx.y >> 3;     // E/256 = 8 e-blocks
  const int eblk = blockIdx.y & 7;
  const int e    = eblk * 256 + threadIdx.x;
  const float a  = aexp[e];
  const bf16_t* up = u + ((size_t)(b * Sdim + c * CL)) * Edim + e;
  float z = 0.f;
  #pragma unroll
  for (int t = 0; t < CL; ++t) z = fmaf(a, z, (float)up[(size_t)t * Edim]);
  zloc[((size_t)b * CH + c) * Edim + e] = z;
}

// Phase 2: exclusive prefix over chunks: zloc[c] <- state at chunk c start
__global__ __launch_bounds__(256)
void scan_part2(const float* __restrict__ aexp, float* __restrict__ zloc) {
  const int idx = blockIdx.x * 256 + threadIdx.x;  // b*E + e
  const int b = idx >> 11, e = idx & (Edim - 1);
  float a  = aexp[e];
  float aL = a * a;           // a^2
  aL = aL * aL;               // a^4
  aL = aL * aL;               // a^8
  aL = aL * aL;               // a^16
  aL = aL * aL;               // a^32 == a^CL
  float* zp = zloc + (size_t)b * CH * Edim + e;
  float pref = 0.f;
  #pragma unroll 4
  for (int c = 0; c < CH; ++c) {
    const float loc = zp[(size_t)c * Edim];
    zp[(size_t)c * Edim] = pref;
    pref = fmaf(aL, pref, loc);
  }
}

// Phase 3: re-scan with start state, gate, write xg
__global__ __launch_bounds__(256)
void scan_part3(const bf16_t* __restrict__ u, const bf16_t* __restrict__ xpg,
                const float* __restrict__ aexp, const float* __restrict__ Ce,
                const float* __restrict__ zloc, bf16_t* __restrict__ xg) {
  const int c    = blockIdx.x;
  const int b    = blockIdx.y >> 3;
  const int eblk = blockIdx.y & 7;
  const int e    = eblk * 256 + threadIdx.x;
  const float a = aexp[e], C = Ce[e];
  float z = zloc[((size_t)b * CH + c) * Edim + e];
  const bf16_t* up = u   + ((size_t)(b * Sdim + c * CL)) * Edim + e;
  const bf16_t* gp = xpg + ((size_t)(b * Sdim + c * CL)) * (2 * Edim) + Edim + e;
  bf16_t*       op = xg  + ((size_t)(b * Sdim + c * CL)) * Edim + e;
  #pragma unroll 8
  for (int t = 0; t < CL; ++t) {
    z = fmaf(a, z, (float)up[(size_t)t * Edim]);
    const float gv = (float)gp[(size_t)t * (2 * Edim)];
    op[(size_t)t * Edim] = (bf16_t)(C * z * sigmoidf_(gv));
  }
}

extern "C" void kernel_launch(void* const* d_in, const int* in_sizes, int n_in,
                              void* d_out, int out_size, void* d_ws, size_t ws_size,
                              hipStream_t stream) {
  const float* x         = (const float*)d_in[0];
  const float* ln_g      = (const float*)d_in[1];
  const float* ln_b      = (const float*)d_in[2];
  const float* W_in      = (const float*)d_in[3];
  const float* b_in      = (const float*)d_in[4];
  const float* conv_w    = (const float*)d_in[5];
  const float* conv_b    = (const float*)d_in[6];
  const float* Am        = (const float*)d_in[7];
  const float* Bm        = (const float*)d_in[8];
  const float* W_c       = (const float*)d_in[9];
  const float* b_c       = (const float*)d_in[10];
  const float* W_d       = (const float*)d_in[11];
  const float* b_d       = (const float*)d_in[12];
  const float* log_delta = (const float*)d_in[13];
  const float* W_out     = (const float*)d_in[14];
  const float* b_out     = (const float*)d_in[15];
  float* out = (float*)d_out;

  const size_t MiB = 1024 * 1024;
  char* w = (char*)d_ws;
  bf16_t* wWin  = (bf16_t*)(w + 0);           //  8 MiB  (4096x1024)
  bf16_t* wWc   = (bf16_t*)(w + 8 * MiB);     //  8 MiB  (2048x2048)
  bf16_t* wWd   = (bf16_t*)(w + 16 * MiB);    //  8 MiB
  bf16_t* wWout = (bf16_t*)(w + 24 * MiB);    //  4 MiB  (1024x2048)
  float*  aexp  = (float*) (w + 28 * MiB);    //  8 KiB
  float*  Ce    = (float*) (w + 28 * MiB + 16384);
  float*  zloc  = (float*) (w + 28 * MiB + 65536);  // 2 MiB (B*CH*E fp32)
  bf16_t* xln   = (bf16_t*)(w + 31 * MiB);    // 16 MiB  (8192x1024)
  bf16_t* xpg   = (bf16_t*)(w + 47 * MiB);    // 64 MiB  (8192x4096)
  bf16_t* xc    = (bf16_t*)(w + 111 * MiB);   // 32 MiB  (8192x2048)
  bf16_t* cbuf  = (bf16_t*)(w + 143 * MiB);   // 32 MiB  (c, then u in-place)
  bf16_t* dbuf  = (bf16_t*)(w + 175 * MiB);   // 32 MiB  (xg) -> ends 207 MiB

  const int M = Bdim * Sdim;  // 8192

  // weights -> bf16
  cvt_bf16<<<(2 * Edim * Ddim) / 256, 256, 0, stream>>>(W_in, wWin, 2 * Edim * Ddim);
  cvt_bf16<<<(Edim * Edim) / 256, 256, 0, stream>>>(W_c, wWc, Edim * Edim);
  cvt_bf16<<<(Edim * Edim) / 256, 256, 0, stream>>>(W_d, wWd, Edim * Edim);
  cvt_bf16<<<(Ddim * Edim) / 256, 256, 0, stream>>>(W_out, wWout, Ddim * Edim);
  prep_scalars<<<Edim / 256, 256, 0, stream>>>(log_delta, Am, Bm, aexp, Ce);

  // layernorm
  ln_kernel<<<M, 256, 0, stream>>>(x, ln_g, ln_b, xln);

  // x_proj = x_ln @ W_in^T + b_in   -> xpg (bf16, 8192x4096)
  gemm_bt<0><<<dim3((2 * Edim) / BN, M / BM), 256, 0, stream>>>(
      xln, wWin, b_in, nullptr, nullptr, xpg, nullptr, M, 2 * Edim, Ddim);

  // causal conv + silu -> xc
  conv_silu<<<dim3(Bdim * (Sdim / 4), Edim / 256), 256, 0, stream>>>(xpg, conv_w, conv_b, xc);

  // c = xc @ W_c^T + b_c
  gemm_bt<0><<<dim3(Edim / BN, M / BM), 256, 0, stream>>>(
      xc, wWc, b_c, nullptr, nullptr, cbuf, nullptr, M, Edim, Edim);
  // u = c * sigmoid(xc @ W_d^T + b_d)   (fused epilogue, u -> cbuf in place)
  gemm_bt<2><<<dim3(Edim / BN, M / BM), 256, 0, stream>>>(
      xc, wWd, b_d, nullptr, cbuf, cbuf, nullptr, M, Edim, Edim);

  // chunked scan + gate -> xg (dbuf)
  scan_part1<<<dim3(CH, Bdim * (Edim / 256)), 256, 0, stream>>>(cbuf, aexp, zloc);
  scan_part2<<<(Bdim * Edim) / 256, 256, 0, stream>>>(aexp, zloc);
  scan_part3<<<dim3(CH, Bdim * (Edim / 256)), 256, 0, stream>>>(cbuf, xpg, aexp, Ce, zloc, dbuf);

  // out = xg @ W_out^T + b_out + x
  gemm_bt<1><<<dim3(Ddim / BN, M / BM), 256, 0, stream>>>(
      dbuf, wWout, b_out, x, nullptr, nullptr, out, M, Ddim, Edim);

  (void)in_sizes; (void)n_in; (void)out_size; (void)ws_size;
}